// Round 4
// baseline (120.445 us; speedup 1.0000x reference)
//
#include <hip/hip_runtime.h>
#include <hip/hip_bf16.h>

#define N_NODES 8192
#define DIN     512
#define DOUT    256
#define ALPHA   0.2f
#define LOG2E   1.4426950408889634f

typedef __bf16 bf16x8 __attribute__((ext_vector_type(8)));
typedef __bf16 bf16x4 __attribute__((ext_vector_type(4)));
typedef float  f32x4  __attribute__((ext_vector_type(4)));
typedef int    i32x4  __attribute__((ext_vector_type(4)));

#define MFMA16 __builtin_amdgcn_mfma_f32_16x16x32_bf16

// async global->LDS, 16B per lane, dest = uniform base + lane*16
__device__ __forceinline__ void gld16(const int* g, int* l) {
    __builtin_amdgcn_global_load_lds(
        (const __attribute__((address_space(1))) void*)g,
        (__attribute__((address_space(3))) void*)l, 16, 0, 0);
}

// ---------------------------------------------------------------------------
// A0: repack weight f32 [512][256] -> wB bf16 fragment layout. Zeroes kmaxkey.
__global__ __launch_bounds__(256) void k_repack_w(const float* __restrict__ w,
                                                  bf16x8* __restrict__ wB,
                                                  unsigned* __restrict__ kmaxkey) {
    if (blockIdx.x == 0 && threadIdx.x == 0) *kmaxkey = 0u;
    int u = blockIdx.x * 256 + threadIdx.x;   // 16384 units
    int lane = u & 63, t = u >> 6;
    int nt = t & 15, kt = t >> 4;
    int k0 = kt * 32 + (lane >> 4) * 8;
    int col = nt * 16 + (lane & 15);
    bf16x8 r;
#pragma unroll
    for (int i = 0; i < 8; ++i) r[i] = (__bf16)w[(size_t)(k0 + i) * DOUT + col];
    wB[u] = r;
}

// ---------------------------------------------------------------------------
// A1 (fused): v = node @ weight in registers; emits vB fragments (LDS bounce),
// Q/K scalars, global K-max.
__global__ __launch_bounds__(256) void k_gemm1f(const float* __restrict__ node,
                                                const bf16x8* __restrict__ wB,
                                                const float* __restrict__ a,
                                                bf16x8* __restrict__ vBo,
                                                float* __restrict__ Q, float* __restrict__ K,
                                                unsigned* __restrict__ kmaxkey) {
    __shared__ __bf16 vsh[32][260];   // +4 pad
    __shared__ float qksh[32][2];
    int lane = threadIdx.x & 63, w = threadIdx.x >> 6;
    int r15 = lane & 15, g = lane >> 4;
    int nh = w & 1, rh = w >> 1;
    int rowbase = blockIdx.x * 32;
    int myrow = rowbase + rh * 16 + r15;
    const float* np = node + (size_t)myrow * DIN + g * 8;

    f32x4 acc[8];
#pragma unroll
    for (int j = 0; j < 8; ++j) acc[j] = (f32x4){0.f, 0.f, 0.f, 0.f};

    f32x4 c0 = *(const f32x4*)np;
    f32x4 c1 = *(const f32x4*)(np + 4);
    f32x4 c2 = *(const f32x4*)(np + 32);
    f32x4 c3 = *(const f32x4*)(np + 36);
    const bf16x8* wp = wB + (size_t)(nh * 8) * 64 + lane;
    bf16x8 fr0 = wp[0], fr1 = wp[64], fr2 = wp[128], fr3 = wp[192];
    bf16x8 fr4 = wp[256], fr5 = wp[320], fr6 = wp[384], fr7 = wp[448];

    for (int kt = 0; kt < 16; ++kt) {
        f32x4 u0 = c0, u1 = c1;
        c0 = c2; c1 = c3;
        if (kt + 2 < 16) {
            c2 = *(const f32x4*)(np + (kt + 2) * 32);
            c3 = *(const f32x4*)(np + (kt + 2) * 32 + 4);
        }
        bf16x8 f0 = fr0, f1 = fr1, f2 = fr2, f3 = fr3;
        bf16x8 f4 = fr4, f5 = fr5, f6 = fr6, f7 = fr7;
        if (kt + 1 < 16) {
            const bf16x8* wn = wB + ((size_t)(kt + 1) * 16 + nh * 8) * 64 + lane;
            fr0 = wn[0]; fr1 = wn[64]; fr2 = wn[128]; fr3 = wn[192];
            fr4 = wn[256]; fr5 = wn[320]; fr6 = wn[384]; fr7 = wn[448];
        }
        bf16x8 af;
#pragma unroll
        for (int i = 0; i < 4; ++i) { af[i] = (__bf16)u0[i]; af[i + 4] = (__bf16)u1[i]; }
        acc[0] = MFMA16(af, f0, acc[0], 0, 0, 0);
        acc[1] = MFMA16(af, f1, acc[1], 0, 0, 0);
        acc[2] = MFMA16(af, f2, acc[2], 0, 0, 0);
        acc[3] = MFMA16(af, f3, acc[3], 0, 0, 0);
        acc[4] = MFMA16(af, f4, acc[4], 0, 0, 0);
        acc[5] = MFMA16(af, f5, acc[5], 0, 0, 0);
        acc[6] = MFMA16(af, f6, acc[6], 0, 0, 0);
        acc[7] = MFMA16(af, f7, acc[7], 0, 0, 0);
    }

    float qp0 = 0.f, qp1 = 0.f, qp2 = 0.f, qp3 = 0.f;
    float kp0 = 0.f, kp1 = 0.f, kp2 = 0.f, kp3 = 0.f;
#pragma unroll
    for (int j = 0; j < 8; ++j) {
        int col = (nh * 8 + j) * 16 + r15;
        float a1 = a[col], a2 = a[DOUT + col];
        qp0 += acc[j][0] * a1; qp1 += acc[j][1] * a1;
        qp2 += acc[j][2] * a1; qp3 += acc[j][3] * a1;
        kp0 += acc[j][0] * a2; kp1 += acc[j][1] * a2;
        kp2 += acc[j][2] * a2; kp3 += acc[j][3] * a2;
    }
#pragma unroll
    for (int m = 1; m < 16; m <<= 1) {
        qp0 += __shfl_xor(qp0, m); qp1 += __shfl_xor(qp1, m);
        qp2 += __shfl_xor(qp2, m); qp3 += __shfl_xor(qp3, m);
        kp0 += __shfl_xor(kp0, m); kp1 += __shfl_xor(kp1, m);
        kp2 += __shfl_xor(kp2, m); kp3 += __shfl_xor(kp3, m);
    }

#pragma unroll
    for (int j = 0; j < 8; ++j)
#pragma unroll
        for (int r = 0; r < 4; ++r)
            vsh[rh * 16 + g * 4 + r][(nh * 8 + j) * 16 + r15] = (__bf16)acc[j][r];
    if (nh == 0 && r15 == 0) {
        int rl = rh * 16 + g * 4;
        qksh[rl + 0][0] = qp0; qksh[rl + 1][0] = qp1; qksh[rl + 2][0] = qp2; qksh[rl + 3][0] = qp3;
        qksh[rl + 0][1] = kp0; qksh[rl + 1][1] = kp1; qksh[rl + 2][1] = kp2; qksh[rl + 3][1] = kp3;
    }
    __syncthreads();
    if (nh == 1 && r15 == 0) {
        int rl = rh * 16 + g * 4;
        int rw = rowbase + rl;
        float q0 = qp0 + qksh[rl + 0][0], q1 = qp1 + qksh[rl + 1][0];
        float q2 = qp2 + qksh[rl + 2][0], q3 = qp3 + qksh[rl + 3][0];
        float k0 = kp0 + qksh[rl + 0][1], k1 = kp1 + qksh[rl + 1][1];
        float k2 = kp2 + qksh[rl + 2][1], k3 = kp3 + qksh[rl + 3][1];
        Q[rw + 0] = q0; Q[rw + 1] = q1; Q[rw + 2] = q2; Q[rw + 3] = q3;
        K[rw + 0] = k0; K[rw + 1] = k1; K[rw + 2] = k2; K[rw + 3] = k3;
        float km = fmaxf(fmaxf(k0, k1), fmaxf(k2, k3));
        unsigned bits = __float_as_uint(km);
        unsigned key = (bits & 0x80000000u) ? ~bits : (bits | 0x80000000u);
        atomicMax(kmaxkey, key);
    }
#pragma unroll
    for (int uu = 0; uu < 4; ++uu) {
        int nt = w * 4 + uu;
        bf16x8 t;
#pragma unroll
        for (int i = 0; i < 8; ++i) t[i] = vsh[g * 8 + i][nt * 16 + r15];
        vBo[((size_t)blockIdx.x * 16 + nt) * 64 + lane] = t;
    }
}

// ---------------------------------------------------------------------------
// B (round-4 REWRITE): barrier-free masked-softmax-numerator GEMM.
// Each wave owns 32 P-rows x all 256 cols (block = 128 rows): the P fragment
// a lane computes IS the MFMA A-operand (row=lane&15, k=g*8+i) -> no pT LDS
// bounce, no Ms, no ballots, NO per-step barrier. Waves free-run.
// Adj: per-wave ring-2 LDS chunks (32 rows x 64 cols) staged with
// global_load_lds; LDS dest linear, global SOURCE pre-swizzled
// (col = 4*((lane&15)^(row&7))) so consume-side ds_read_b128 at
// o = (row*64+h*32+g*8)^((row&7)<<2), o^4 is bank-conflict-free.
// Fencing: stage instrs issued (mid-step, after this step's B-loads; pinned
// by sched_barrier) are drained by the compiler's vmcnt wait for the NEXT
// step's B-fragment loads -- one full step before first LDS read. Chunk 0
// drained by the prologue __syncthreads.
// vB B-frags re-read per wave from L1/L2 (per-XCD window 512KB, L2-hot);
// bare s_barrier every 4 steps keeps waves phase-aligned for L1 reuse.
template<int JS>
__global__ __launch_bounds__(256, 2) void k_attn2(const int* __restrict__ adj,
                                                  const bf16x8* __restrict__ vBg,
                                                  const float* __restrict__ Q,
                                                  const float* __restrict__ K,
                                                  const unsigned* __restrict__ kmaxkey,
                                                  __bf16* __restrict__ accB,
                                                  float* __restrict__ Sp) {
    constexpr int JR  = N_NODES / JS;   // cols per p-slice
    constexpr int BIT = JR / 32;        // k-steps
    constexpr int NCH = JR / 64;        // adj chunks (2 steps each)
    __shared__ float Ks[JR];
    __shared__ int   Ar[2][4][2048];    // [slot][wave][32 rows x 64 ints]

    const int bid = blockIdx.x;
    const int rb = bid / JS, p = bid % JS;     // p round-robins XCDs
    const int lane = threadIdx.x & 63, w = threadIdx.x >> 6;
    const int r15 = lane & 15, g = lane >> 4;
    const int rowbase = rb * 128;
    const int prow0 = rowbase + w * 32 + r15;  // frag0 row; frag1 = +16
    const int j0 = p * JR;

    for (int s = threadIdx.x * 4; s < JR; s += 1024)
        *(f32x4*)&Ks[s] = *(const f32x4*)&K[j0 + s];

    // adj staging: instr t covers rows w*32 + t*4 + (lane>>4); source col
    // pre-swizzled so linear LDS dest yields the swizzled image.
    const int* rlane = adj + (size_t)(rowbase + w * 32 + (lane >> 4)) * N_NODES + j0;
    const int colE = 4 * ((lane & 15) ^ (lane >> 4));        // t even: row&7 = lane>>4
    const int colO = 4 * ((lane & 15) ^ (4 + (lane >> 4)));  // t odd:  row&7 = 4+(lane>>4)

#define STAGE(c) { const int* gp_ = rlane + (c) * 64; int* lp_ = &Ar[(c) & 1][w][0];  \
    _Pragma("unroll") for (int t_ = 0; t_ < 8; ++t_)                                  \
        gld16(gp_ + (size_t)t_ * 4 * N_NODES + ((t_ & 1) ? colO : colE), lp_ + t_ * 256); }

    STAGE(0)

    float qi0 = Q[prow0], qi1 = Q[prow0 + 16];
    unsigned kk = *kmaxkey;
    unsigned kb = (kk & 0x80000000u) ? (kk ^ 0x80000000u) : ~kk;
    float kmax = __uint_as_float(kb);
    float t00 = qi0 + kmax, t01 = qi1 + kmax;
    float c20 = fmaxf(t00, ALPHA * t00) * LOG2E;
    float c21 = fmaxf(t01, ALPHA * t01) * LOG2E;
    float A10 = qi0 * LOG2E - c20, A20 = ALPHA * qi0 * LOG2E - c20;
    float A11 = qi1 * LOG2E - c21, A21 = ALPHA * qi1 * LOG2E - c21;

    f32x4 ac0[16], ac1[16];
#pragma unroll
    for (int nt = 0; nt < 16; ++nt) {
        ac0[nt] = (f32x4){0.f, 0.f, 0.f, 0.f};
        ac1[nt] = (f32x4){0.f, 0.f, 0.f, 0.f};
    }
    float sl0 = 0.f, sl1 = 0.f;

    __syncthreads();   // Ks visible; chunk 0 landed (vmcnt(0) drain)

    const bf16x8* vbp = vBg + (size_t)(p * (JR >> 5)) * 1024 + lane;

    for (int itv = 0; itv < BIT; ++itv) {
        if ((itv & 3) == 0 && itv) __builtin_amdgcn_s_barrier();  // cache pacing only

        const bf16x8* vs = vbp + (size_t)itv * 1024;
        bf16x8 B0[8];
#pragma unroll
        for (int nt = 0; nt < 8; ++nt) B0[nt] = vs[nt * 64];

        f32x4 q0 = *(const f32x4*)&Ks[itv * 32 + g * 8];
        f32x4 q1 = *(const f32x4*)&Ks[itv * 32 + g * 8 + 4];
        const int* ap = &Ar[(itv >> 1) & 1][w][0];
        const int hh = (itv & 1) << 5;

        bf16x8 af0, af1;
        {   // frag0: row r15
            int o = ((r15 * 64) + hh + (g << 3)) ^ ((r15 & 7) << 2);
            i32x4 a0 = *(const i32x4*)(ap + o);
            i32x4 a1 = *(const i32x4*)(ap + (o ^ 4));
#pragma unroll
            for (int i = 0; i < 8; ++i) {
                float kj = (i < 4) ? q0[i] : q1[i - 4];
                float f1 = __builtin_fmaf(kj, LOG2E, A10);
                float f2 = __builtin_fmaf(kj, ALPHA * LOG2E, A20);
                float pv = __builtin_amdgcn_exp2f(fmaxf(f1, f2));
                int av = (i < 4) ? a0[i] : a1[i - 4];
                pv = av ? pv : 0.f;
                sl0 += pv; af0[i] = (__bf16)pv;
            }
        }
        {   // frag1: row r15+16  ((row&7) unchanged)
            int o = (((r15 + 16) * 64) + hh + (g << 3)) ^ ((r15 & 7) << 2);
            i32x4 a0 = *(const i32x4*)(ap + o);
            i32x4 a1 = *(const i32x4*)(ap + (o ^ 4));
#pragma unroll
            for (int i = 0; i < 8; ++i) {
                float kj = (i < 4) ? q0[i] : q1[i - 4];
                float f1 = __builtin_fmaf(kj, LOG2E, A11);
                float f2 = __builtin_fmaf(kj, ALPHA * LOG2E, A21);
                float pv = __builtin_amdgcn_exp2f(fmaxf(f1, f2));
                int av = (i < 4) ? a0[i] : a1[i - 4];
                pv = av ? pv : 0.f;
                sl1 += pv; af1[i] = (__bf16)pv;
            }
        }

        bf16x8 B1[8];
#pragma unroll
        for (int nt = 0; nt < 8; ++nt) B1[nt] = vs[(nt + 8) * 64];

        // stage next chunk mid-step, AFTER this step's B-loads so the B-waits
        // don't drain it; next step's B-wait fences it before first read.
        if (!(itv & 1)) {
            int c = (itv >> 1) + 1;
            if (c < NCH) { STAGE(c) }
            __builtin_amdgcn_sched_barrier(0);
        }

#pragma unroll
        for (int nt = 0; nt < 8; ++nt) {
            ac0[nt] = MFMA16(af0, B0[nt], ac0[nt], 0, 0, 0);
            ac1[nt] = MFMA16(af1, B0[nt], ac1[nt], 0, 0, 0);
        }
#pragma unroll
        for (int nt = 0; nt < 8; ++nt) {
            ac0[nt + 8] = MFMA16(af0, B1[nt], ac0[nt + 8], 0, 0, 0);
            ac1[nt + 8] = MFMA16(af1, B1[nt], ac1[nt + 8], 0, 0, 0);
        }
    }
#undef STAGE

    // denominators: rows keyed by r15; reduce over g (lanes ^16, ^32)
    sl0 += __shfl_xor(sl0, 16); sl0 += __shfl_xor(sl0, 32);
    sl1 += __shfl_xor(sl1, 16); sl1 += __shfl_xor(sl1, 32);
    if (lane < 16) {
        Sp[(size_t)p * N_NODES + prow0] = sl0;
        Sp[(size_t)p * N_NODES + prow0 + 16] = sl1;
    }

    // store permuted bf16 partials: phys col = r15*16 + nt <-> logical nt*16+r15
    __bf16* apb = accB + ((size_t)p * N_NODES + rowbase + w * 32) * DOUT;
#pragma unroll
    for (int reg = 0; reg < 4; ++reg) {
        bf16x8 s0, s1, s2, s3;
#pragma unroll
        for (int nt = 0; nt < 8; ++nt) {
            s0[nt] = (__bf16)ac0[nt][reg];     s1[nt] = (__bf16)ac0[nt + 8][reg];
            s2[nt] = (__bf16)ac1[nt][reg];     s3[nt] = (__bf16)ac1[nt + 8][reg];
        }
        size_t r0 = (size_t)(g * 4 + reg) * DOUT + r15 * 16;
        size_t r1 = (size_t)(16 + g * 4 + reg) * DOUT + r15 * 16;
        *(bf16x8*)&apb[r0] = s0;     *(bf16x8*)&apb[r0 + 8] = s1;
        *(bf16x8*)&apb[r1] = s2;     *(bf16x8*)&apb[r1 + 8] = s3;
    }
}

// ---------------------------------------------------------------------------
// C: combine bf16 partials (permuted layout), softmax denom, leaky-relu,
// L2-normalize, +bias. Wave per row; un-permute on store:
// phys p = lane*4+j  ->  logical col = (p&15)*16 + (p>>4).
template<int JS>
__global__ __launch_bounds__(256) void k_final(const __bf16* __restrict__ accB,
                                               const float* __restrict__ Sp,
                                               const float* __restrict__ bias,
                                               float* __restrict__ out) {
    int lane = threadIdx.x & 63, wv = threadIdx.x >> 6;
    int row = blockIdx.x * 4 + wv;
    float s = 0.f;
    f32x4 av = (f32x4){0.f, 0.f, 0.f, 0.f};
#pragma unroll
    for (int pp = 0; pp < JS; ++pp) {
        bf16x4 t = *(const bf16x4*)&accB[((size_t)pp * N_NODES + row) * DOUT + lane * 4];
#pragma unroll
        for (int j = 0; j < 4; ++j) av[j] += (float)t[j];
        s += Sp[(size_t)pp * N_NODES + row];
    }
    float inv = 1.0f / fmaxf(s, 1e-30f);
    f32x4 o;
#pragma unroll
    for (int j = 0; j < 4; ++j) {
        float x = av[j] * inv;
        o[j] = fmaxf(x, ALPHA * x);
    }
    float sq = o[0] * o[0] + o[1] * o[1] + o[2] * o[2] + o[3] * o[3];
#pragma unroll
    for (int m = 1; m < 64; m <<= 1) sq += __shfl_xor(sq, m);
    float innrm = 1.0f / fmaxf(sqrtf(sq), 1e-12f);
#pragma unroll
    for (int j = 0; j < 4; ++j) {
        int col = ((lane & 3) * 4 + j) * 16 + (lane >> 2);
        out[(size_t)row * DOUT + col] = o[j] * innrm + bias[col];
    }
}

// ---------------------------------------------------------------------------
extern "C" void kernel_launch(void* const* d_in, const int* in_sizes, int n_in,
                              void* d_out, int out_size, void* d_ws, size_t ws_size,
                              hipStream_t stream) {
    const float* node   = (const float*)d_in[0];
    const int*   adj    = (const int*)d_in[1];
    const float* weight = (const float*)d_in[2];
    const float* a      = (const float*)d_in[3];
    const float* bias   = (const float*)d_in[4];
    float* out = (float*)d_out;

    const size_t fixed  = 4522240;                 // wB 256K + vB 4M + Q/K 64K + kmax
    const size_t per_js = 32768 + (size_t)N_NODES * DOUT * 2;   // Sp + accB(bf16)
    int js = (ws_size >= fixed + 8 * per_js) ? 8 : 4;

    char* ws = (char*)d_ws;
    bf16x8*   wB      = (bf16x8*)(ws);
    bf16x8*   vB      = (bf16x8*)(ws + 262144);
    float*    Q       = (float*)(ws + 4456448);
    float*    K       = (float*)(ws + 4489216);
    unsigned* kmaxkey = (unsigned*)(ws + 4521984);
    float*    Sp      = (float*)(ws + fixed);
    __bf16*   accB    = (__bf16*)(ws + fixed + (size_t)js * 32768);

    k_repack_w<<<dim3(64),  dim3(256), 0, stream>>>(weight, wB, kmaxkey);
    k_gemm1f  <<<dim3(256), dim3(256), 0, stream>>>(node, wB, a, vB, Q, K, kmaxkey);
    if (js == 8) {
        k_attn2<8><<<dim3(64 * 8), dim3(256), 0, stream>>>(adj, vB, Q, K, kmaxkey, accB, Sp);
        k_final<8><<<dim3(2048), dim3(256), 0, stream>>>(accB, Sp, bias, out);
    } else {
        k_attn2<4><<<dim3(64 * 4), dim3(256), 0, stream>>>(adj, vB, Q, K, kmaxkey, accB, Sp);
        k_final<4><<<dim3(2048), dim3(256), 0, stream>>>(accB, Sp, bias, out);
    }
}